// Round 1
// baseline (428.431 us; speedup 1.0000x reference)
//
#include <hip/hip_runtime.h>

// Attention block: B=16, C=512, H=W=32 (N=1024), GROUPS=8, EPS=1e-5
// x:[B,C,N] f32, gamma/beta:[C], w_qkv:[1536,512], b_qkv:[1536],
// w_proj:[512,512], b_proj:[512]. out = x + proj.
//
// Workspace layout (needs ~151 MB):
//   hn      bf16 [B][512][1024]   16,777,216 B
//   qkv     bf16 [B][1536][1024]  50,331,648 B
//   attnout bf16 [B][512][1024]   16,777,216 B
//   S       f32  [B][1024][1024]  67,108,864 B   (softmaxed in place)

#define BATCH 16
#define CCH 512
#define NSP 1024
#define NGRP 8
#define EPSV 1e-5f
#define LDP 40  // padded LDS row stride (shorts); 80 B, 16B-aligned

typedef short bf16x8 __attribute__((ext_vector_type(8)));
typedef float f32x4 __attribute__((ext_vector_type(4)));

__device__ __forceinline__ unsigned short f2bf(float f) {
    unsigned int u = __float_as_uint(f);
    u += 0x7FFF + ((u >> 16) & 1);  // round-to-nearest-even
    return (unsigned short)(u >> 16);
}

// ---------------- GroupNorm -> bf16 hn ----------------
__global__ __launch_bounds__(1024) void groupnorm_k(
    const float* __restrict__ x, const float* __restrict__ gamma,
    const float* __restrict__ beta, unsigned short* __restrict__ hn) {
    const int b = blockIdx.x >> 3, g = blockIdx.x & 7;
    const size_t base = ((size_t)b * CCH + (size_t)g * 64) * NSP;  // floats
    const float4* xp = (const float4*)(x + base);
    const int t = threadIdx.x;
    float s = 0.f, q = 0.f;
    float4 vals[16];
#pragma unroll
    for (int i = 0; i < 16; i++) {
        float4 v = xp[t + i * 1024];
        vals[i] = v;
        s += v.x + v.y + v.z + v.w;
        q += v.x * v.x + v.y * v.y + v.z * v.z + v.w * v.w;
    }
    // wave reduce (64-wide)
#pragma unroll
    for (int off = 32; off; off >>= 1) {
        s += __shfl_down(s, off);
        q += __shfl_down(q, off);
    }
    __shared__ float rs[16], rq[16], mv[2];
    const int wave = t >> 6, lane = t & 63;
    if (lane == 0) { rs[wave] = s; rq[wave] = q; }
    __syncthreads();
    if (t == 0) {
        float S = 0.f, Q = 0.f;
        for (int i = 0; i < 16; i++) { S += rs[i]; Q += rq[i]; }
        const float inv = 1.f / 65536.f;
        float mean = S * inv;
        float var = Q * inv - mean * mean;
        mv[0] = mean;
        mv[1] = rsqrtf(var + EPSV);
    }
    __syncthreads();
    const float mean = mv[0], rstd = mv[1];
    ushort4* hp = (ushort4*)(hn + base);
#pragma unroll
    for (int i = 0; i < 16; i++) {
        int f = t + i * 1024;
        int c = g * 64 + (f >> 8);
        float ga = gamma[c] * rstd, be = beta[c] - mean * gamma[c] * rstd;
        float4 v = vals[i];
        ushort4 o;
        o.x = f2bf(v.x * ga + be);
        o.y = f2bf(v.y * ga + be);
        o.z = f2bf(v.z * ga + be);
        o.w = f2bf(v.w * ga + be);
        hp[f] = o;
    }
}

// ---------------- GEMM1: qkv = W[1536,512] @ hn[512,1024] + bias ----------------
__global__ __launch_bounds__(256) void gemm_qkv_k(
    const unsigned short* __restrict__ hn, const float* __restrict__ W,
    const float* __restrict__ bias, unsigned short* __restrict__ qkv) {
    const int nt = blockIdx.x * 64;
    const int mt = blockIdx.y * 64;
    const int b = blockIdx.z;
    const unsigned short* hb = hn + (size_t)b * CCH * NSP;
    unsigned short* ob = qkv + (size_t)b * 3 * CCH * NSP;
    __shared__ __align__(16) short Al[64 * LDP];
    __shared__ __align__(16) short Bl[64 * LDP];
    const int t = threadIdx.x, lane = t & 63, w = t >> 6;
    const int ar = t >> 2, ak = (t & 3) * 8;  // A staging
    const int bj = t & 63, bkb = t >> 6;      // B staging (transpose pattern)
    const int fr = lane & 15, fk = (lane >> 4) * 8;
    f32x4 acc[4];
#pragma unroll
    for (int ct = 0; ct < 4; ct++)
#pragma unroll
        for (int r = 0; r < 4; r++) acc[ct][r] = 0.f;
    for (int k0 = 0; k0 < 512; k0 += 32) {
        const float* wp = W + (size_t)(mt + ar) * 512 + k0 + ak;
        short* ap = Al + ar * LDP + ak;
#pragma unroll
        for (int j = 0; j < 8; j++) ap[j] = (short)f2bf(wp[j]);
#pragma unroll
        for (int r = 0; r < 8; r++) {
            int k = k0 + bkb + 4 * r;
            Bl[bj * LDP + bkb + 4 * r] = (short)hb[(size_t)k * NSP + nt + bj];
        }
        __syncthreads();
        bf16x8 a = *(const bf16x8*)(Al + (16 * w + fr) * LDP + fk);
#pragma unroll
        for (int ct = 0; ct < 4; ct++) {
            bf16x8 bb = *(const bf16x8*)(Bl + (16 * ct + fr) * LDP + fk);
            acc[ct] = __builtin_amdgcn_mfma_f32_16x16x32_bf16(a, bb, acc[ct], 0, 0, 0);
        }
        __syncthreads();
    }
    const int dr0 = 16 * w + (lane >> 4) * 4;
#pragma unroll
    for (int ct = 0; ct < 4; ct++) {
        int col = nt + 16 * ct + fr;
#pragma unroll
        for (int r = 0; r < 4; r++) {
            int row = mt + dr0 + r;
            ob[(size_t)row * NSP + col] = f2bf(acc[ct][r] + bias[row]);
        }
    }
}

// ---------------- GEMM2: S[n,m] = scale * sum_c Q[c,n] K[c,m] ----------------
__global__ __launch_bounds__(256) void gemm_scores_k(
    const unsigned short* __restrict__ qkv, float* __restrict__ S) {
    const int nt = blockIdx.x * 64;  // key tile
    const int mt = blockIdx.y * 64;  // query tile
    const int b = blockIdx.z;
    const unsigned short* Q = qkv + (size_t)b * 3 * CCH * NSP;
    const unsigned short* Km = Q + (size_t)CCH * NSP;
    float* Sb = S + (size_t)b * NSP * NSP;
    __shared__ __align__(16) short Al[64 * LDP];
    __shared__ __align__(16) short Bl[64 * LDP];
    const int t = threadIdx.x, lane = t & 63, w = t >> 6;
    const int sj = t & 63, skb = t >> 6;
    const int fr = lane & 15, fk = (lane >> 4) * 8;
    f32x4 acc[4];
#pragma unroll
    for (int ct = 0; ct < 4; ct++)
#pragma unroll
        for (int r = 0; r < 4; r++) acc[ct][r] = 0.f;
    for (int k0 = 0; k0 < 512; k0 += 32) {
#pragma unroll
        for (int r = 0; r < 8; r++) {
            int k = k0 + skb + 4 * r;
            Al[sj * LDP + skb + 4 * r] = (short)Q[(size_t)k * NSP + mt + sj];
            Bl[sj * LDP + skb + 4 * r] = (short)Km[(size_t)k * NSP + nt + sj];
        }
        __syncthreads();
        bf16x8 a = *(const bf16x8*)(Al + (16 * w + fr) * LDP + fk);
#pragma unroll
        for (int ct = 0; ct < 4; ct++) {
            bf16x8 bb = *(const bf16x8*)(Bl + (16 * ct + fr) * LDP + fk);
            acc[ct] = __builtin_amdgcn_mfma_f32_16x16x32_bf16(a, bb, acc[ct], 0, 0, 0);
        }
        __syncthreads();
    }
    const float scale = 0.044194173824159216f;  // 512^-0.5
    const int dr0 = 16 * w + (lane >> 4) * 4;
#pragma unroll
    for (int ct = 0; ct < 4; ct++) {
        int col = nt + 16 * ct + fr;
#pragma unroll
        for (int r = 0; r < 4; r++) {
            int row = mt + dr0 + r;
            Sb[(size_t)row * NSP + col] = acc[ct][r] * scale;
        }
    }
}

// ---------------- Softmax over rows of S (in place) ----------------
__global__ __launch_bounds__(256) void softmax_k(float* __restrict__ S) {
    const int t = threadIdx.x;
    float* row = S + (size_t)blockIdx.x * NSP;
    float4 v = ((float4*)row)[t];
    float m = fmaxf(fmaxf(v.x, v.y), fmaxf(v.z, v.w));
#pragma unroll
    for (int off = 32; off; off >>= 1) m = fmaxf(m, __shfl_down(m, off));
    __shared__ float red[4];
    __shared__ float bc;
    const int wave = t >> 6, lane = t & 63;
    if (lane == 0) red[wave] = m;
    __syncthreads();
    if (t == 0) bc = fmaxf(fmaxf(red[0], red[1]), fmaxf(red[2], red[3]));
    __syncthreads();
    const float M = bc;
    v.x = __expf(v.x - M);
    v.y = __expf(v.y - M);
    v.z = __expf(v.z - M);
    v.w = __expf(v.w - M);
    float s = v.x + v.y + v.z + v.w;
#pragma unroll
    for (int off = 32; off; off >>= 1) s += __shfl_down(s, off);
    __syncthreads();  // protect red[] reuse
    if (lane == 0) red[wave] = s;
    __syncthreads();
    if (t == 0) bc = red[0] + red[1] + red[2] + red[3];
    __syncthreads();
    const float inv = 1.f / bc;
    v.x *= inv; v.y *= inv; v.z *= inv; v.w *= inv;
    ((float4*)row)[t] = v;
}

// ---------------- GEMM3: attnout[c,n] = sum_m V[c,m] P[n,m] ----------------
__global__ __launch_bounds__(256) void gemm_out_k(
    const unsigned short* __restrict__ qkv, const float* __restrict__ S,
    unsigned short* __restrict__ attnout) {
    const int nt = blockIdx.x * 64;  // query tile
    const int mt = blockIdx.y * 64;  // channel tile
    const int b = blockIdx.z;
    const unsigned short* V = qkv + (size_t)b * 3 * CCH * NSP + (size_t)2 * CCH * NSP;
    const float* P = S + (size_t)b * NSP * NSP;
    unsigned short* ob = attnout + (size_t)b * CCH * NSP;
    __shared__ __align__(16) short Al[64 * LDP];
    __shared__ __align__(16) short Bl[64 * LDP];
    const int t = threadIdx.x, lane = t & 63, w = t >> 6;
    const int ar = t >> 2, ak = (t & 3) * 8;
    const int fr = lane & 15, fk = (lane >> 4) * 8;
    f32x4 acc[4];
#pragma unroll
    for (int ct = 0; ct < 4; ct++)
#pragma unroll
        for (int r = 0; r < 4; r++) acc[ct][r] = 0.f;
    for (int k0 = 0; k0 < 1024; k0 += 32) {
        const unsigned short* vp = V + (size_t)(mt + ar) * NSP + k0 + ak;
        short* ap = Al + ar * LDP + ak;
#pragma unroll
        for (int j = 0; j < 8; j++) ap[j] = (short)vp[j];
        const float* pp = P + (size_t)(nt + ar) * NSP + k0 + ak;
        short* bp = Bl + ar * LDP + ak;
#pragma unroll
        for (int j = 0; j < 8; j++) bp[j] = (short)f2bf(pp[j]);
        __syncthreads();
        bf16x8 a = *(const bf16x8*)(Al + (16 * w + fr) * LDP + fk);
#pragma unroll
        for (int ct = 0; ct < 4; ct++) {
            bf16x8 bb = *(const bf16x8*)(Bl + (16 * ct + fr) * LDP + fk);
            acc[ct] = __builtin_amdgcn_mfma_f32_16x16x32_bf16(a, bb, acc[ct], 0, 0, 0);
        }
        __syncthreads();
    }
    const int dr0 = 16 * w + (lane >> 4) * 4;
#pragma unroll
    for (int ct = 0; ct < 4; ct++) {
        int col = nt + 16 * ct + fr;
#pragma unroll
        for (int r = 0; r < 4; r++) {
            int row = mt + dr0 + r;
            ob[(size_t)row * NSP + col] = f2bf(acc[ct][r]);
        }
    }
}

// ---------------- GEMM4: out = x + b_proj + Wp[512,512] @ attnout ----------------
__global__ __launch_bounds__(256) void gemm_proj_k(
    const unsigned short* __restrict__ attnout, const float* __restrict__ Wp,
    const float* __restrict__ bias, const float* __restrict__ x,
    float* __restrict__ out) {
    const int nt = blockIdx.x * 64;
    const int mt = blockIdx.y * 64;
    const int b = blockIdx.z;
    const unsigned short* hb = attnout + (size_t)b * CCH * NSP;
    __shared__ __align__(16) short Al[64 * LDP];
    __shared__ __align__(16) short Bl[64 * LDP];
    const int t = threadIdx.x, lane = t & 63, w = t >> 6;
    const int ar = t >> 2, ak = (t & 3) * 8;
    const int bj = t & 63, bkb = t >> 6;
    const int fr = lane & 15, fk = (lane >> 4) * 8;
    f32x4 acc[4];
#pragma unroll
    for (int ct = 0; ct < 4; ct++)
#pragma unroll
        for (int r = 0; r < 4; r++) acc[ct][r] = 0.f;
    for (int k0 = 0; k0 < 512; k0 += 32) {
        const float* wp = Wp + (size_t)(mt + ar) * 512 + k0 + ak;
        short* ap = Al + ar * LDP + ak;
#pragma unroll
        for (int j = 0; j < 8; j++) ap[j] = (short)f2bf(wp[j]);
#pragma unroll
        for (int r = 0; r < 8; r++) {
            int k = k0 + bkb + 4 * r;
            Bl[bj * LDP + bkb + 4 * r] = (short)hb[(size_t)k * NSP + nt + bj];
        }
        __syncthreads();
        bf16x8 a = *(const bf16x8*)(Al + (16 * w + fr) * LDP + fk);
#pragma unroll
        for (int ct = 0; ct < 4; ct++) {
            bf16x8 bb = *(const bf16x8*)(Bl + (16 * ct + fr) * LDP + fk);
            acc[ct] = __builtin_amdgcn_mfma_f32_16x16x32_bf16(a, bb, acc[ct], 0, 0, 0);
        }
        __syncthreads();
    }
    const int dr0 = 16 * w + (lane >> 4) * 4;
    const size_t bbase = (size_t)b * CCH * NSP;
#pragma unroll
    for (int ct = 0; ct < 4; ct++) {
        int col = nt + 16 * ct + fr;
#pragma unroll
        for (int r = 0; r < 4; r++) {
            int row = mt + dr0 + r;
            size_t idx = bbase + (size_t)row * NSP + col;
            out[idx] = x[idx] + bias[row] + acc[ct][r];
        }
    }
}

extern "C" void kernel_launch(void* const* d_in, const int* in_sizes, int n_in,
                              void* d_out, int out_size, void* d_ws, size_t ws_size,
                              hipStream_t stream) {
    const float* x = (const float*)d_in[0];
    const float* gamma = (const float*)d_in[1];
    const float* beta = (const float*)d_in[2];
    const float* w_qkv = (const float*)d_in[3];
    const float* b_qkv = (const float*)d_in[4];
    const float* w_proj = (const float*)d_in[5];
    const float* b_proj = (const float*)d_in[6];
    float* out = (float*)d_out;

    char* ws = (char*)d_ws;
    unsigned short* hn = (unsigned short*)ws;                          // 16 MB
    unsigned short* qkv = (unsigned short*)(ws + 16777216);            // 48 MB
    unsigned short* attnout = (unsigned short*)(ws + 16777216 + 50331648);  // 16 MB
    float* S = (float*)(ws + 16777216 + 50331648 + 16777216);          // 64 MB

    groupnorm_k<<<dim3(BATCH * NGRP), dim3(1024), 0, stream>>>(x, gamma, beta, hn);
    gemm_qkv_k<<<dim3(16, 24, BATCH), dim3(256), 0, stream>>>(hn, w_qkv, b_qkv, qkv);
    gemm_scores_k<<<dim3(16, 16, BATCH), dim3(256), 0, stream>>>(qkv, S);
    softmax_k<<<dim3(BATCH * NSP), dim3(256), 0, stream>>>(S);
    gemm_out_k<<<dim3(16, 8, BATCH), dim3(256), 0, stream>>>(qkv, S, attnout);
    gemm_proj_k<<<dim3(16, 8, BATCH), dim3(256), 0, stream>>>(attnout, w_proj, b_proj, x, out);
}

// Round 2
// 258.505 us; speedup vs baseline: 1.6573x; 1.6573x over previous
//
#include <hip/hip_runtime.h>

// Attention block: B=16, C=512, N=1024(=32x32), GROUPS=8, EPS=1e-5
// All GEMMs are NT-form bf16 MFMA (A[M][K] x B[N][K]^T), 128x128 tiles,
// global_load_lds width-16 staging (m97 pattern).
//
// Layouts: hn_t[B][N][C], QKt[B][N][1024] (=[Q|K]), V[B][C][N],
//          S f32 [B][N][N], P bf16 [B][N][N] (aliases QKt),
//          At[B][N][C]. hn_t aliases the start of S (dead by then).

#define BATCH 16
#define CCH 512
#define NSP 1024
#define EPSV 1e-5f
#define BK 32  // shorts per K-step

typedef short bf16x8 __attribute__((ext_vector_type(8)));
typedef float f32x4 __attribute__((ext_vector_type(4)));

__device__ __forceinline__ unsigned short f2bf(float f) {
    unsigned int u = __float_as_uint(f);
    u += 0x7FFF + ((u >> 16) & 1);  // RNE
    return (unsigned short)(u >> 16);
}

__device__ __forceinline__ void glds16(const void* g, void* l) {
    __builtin_amdgcn_global_load_lds(
        (const __attribute__((address_space(1))) unsigned int*)g,
        (__attribute__((address_space(3))) unsigned int*)l, 16, 0, 0);
}

// ---------------- shared 128x128 NT mainloop ----------------
// Ag/Bg point at tile base (row 0 of this block's tile, k=0).
// Strides in shorts. LDS tiles packed [128][BK] (glds forbids padding).
__device__ __forceinline__ void gemm128_loop(
    const unsigned short* __restrict__ Ag, const unsigned short* __restrict__ Bg,
    int astr, int bstr, int ktot, short* Al, short* Bl, f32x4* acc) {
    const int t = threadIdx.x;
    const int w = t >> 6, lane = t & 63;
    const int wr = (w >> 1) * 64, wc = (w & 1) * 64;
    const int fr = lane & 15, fko = (lane >> 4) * 8;
    const int r0 = t >> 2;          // staging row for chunk t (4 chunks/row)
    const int kc = (t & 3) * 8;     // staging k-offset (shorts)
    short* Alb0 = Al + w * 512;     // wave-uniform LDS bases (chunk t)
    short* Alb1 = Al + 2048 + w * 512;  // chunk 256+t
    short* Blb0 = Bl + w * 512;
    short* Blb1 = Bl + 2048 + w * 512;
    for (int k0 = 0; k0 < ktot; k0 += BK) {
        glds16(Ag + (size_t)r0 * astr + k0 + kc, Alb0);
        glds16(Ag + (size_t)(r0 + 64) * astr + k0 + kc, Alb1);
        glds16(Bg + (size_t)r0 * bstr + k0 + kc, Blb0);
        glds16(Bg + (size_t)(r0 + 64) * bstr + k0 + kc, Blb1);
        __syncthreads();
        bf16x8 af[4], bfr[4];
#pragma unroll
        for (int mi = 0; mi < 4; mi++)
            af[mi] = *(const bf16x8*)(Al + (wr + mi * 16 + fr) * BK + fko);
#pragma unroll
        for (int ni = 0; ni < 4; ni++)
            bfr[ni] = *(const bf16x8*)(Bl + (wc + ni * 16 + fr) * BK + fko);
#pragma unroll
        for (int mi = 0; mi < 4; mi++)
#pragma unroll
            for (int ni = 0; ni < 4; ni++)
                acc[mi * 4 + ni] = __builtin_amdgcn_mfma_f32_16x16x32_bf16(
                    af[mi], bfr[ni], acc[mi * 4 + ni], 0, 0, 0);
        __syncthreads();
    }
}

#define EPI_SETUP()                                          \
    const int t = threadIdx.x, lane = t & 63, w = t >> 6;    \
    const int wr = (w >> 1) * 64, wc = (w & 1) * 64;         \
    const int fr = lane & 15, rr0 = (lane >> 4) * 4;

#define ACC_INIT(acc)                                        \
    f32x4 acc[16];                                           \
    _Pragma("unroll") for (int i = 0; i < 16; i++)           \
        acc[i] = (f32x4){0.f, 0.f, 0.f, 0.f};

// ---------------- weight f32 -> bf16 ----------------
__global__ __launch_bounds__(256) void cvt_bf16_k(
    const float* __restrict__ in, unsigned short* __restrict__ out, int n4) {
    int i = blockIdx.x * 256 + threadIdx.x;
    if (i >= n4) return;
    float4 v = ((const float4*)in)[i];
    ushort4 o;
    o.x = f2bf(v.x); o.y = f2bf(v.y); o.z = f2bf(v.z); o.w = f2bf(v.w);
    ((ushort4*)out)[i] = o;
}

// ---------------- GroupNorm stats: one block per (b,g) ----------------
__global__ __launch_bounds__(256) void gn_stats_k(
    const float* __restrict__ x, float* __restrict__ stats) {
    const int bg = blockIdx.x;
    const float4* xp = (const float4*)(x + (size_t)bg * 65536);
    const int t = threadIdx.x;
    float s = 0.f, q = 0.f;
#pragma unroll
    for (int i = 0; i < 64; i++) {
        float4 v = xp[t + i * 256];
        s += v.x + v.y + v.z + v.w;
        q += v.x * v.x + v.y * v.y + v.z * v.z + v.w * v.w;
    }
#pragma unroll
    for (int off = 32; off; off >>= 1) {
        s += __shfl_down(s, off);
        q += __shfl_down(q, off);
    }
    __shared__ float rs[4], rq[4];
    const int wave = t >> 6, lane = t & 63;
    if (lane == 0) { rs[wave] = s; rq[wave] = q; }
    __syncthreads();
    if (t == 0) {
        float S = rs[0] + rs[1] + rs[2] + rs[3];
        float Q = rq[0] + rq[1] + rq[2] + rq[3];
        const float inv = 1.f / 65536.f;
        float mean = S * inv;
        float var = Q * inv - mean * mean;
        stats[bg * 2] = mean;
        stats[bg * 2 + 1] = rsqrtf(var + EPSV);
    }
}

// ---------------- GN normalize + transpose -> hn_t[B][N][C] bf16 --------
__global__ __launch_bounds__(256) void gn_tr_k(
    const float* __restrict__ x, const float* __restrict__ gamma,
    const float* __restrict__ beta, const float* __restrict__ stats,
    unsigned short* __restrict__ hn_t) {
    const int nt = blockIdx.x, ct = blockIdx.y, b = blockIdx.z;
    __shared__ __align__(16) unsigned short T[64 * 72];  // [n][c] +pad
    const int t = threadIdx.x;
    const float mean = stats[(b * 8 + ct) * 2];
    const float rstd = stats[(b * 8 + ct) * 2 + 1];
    const int cl = t >> 2, nc = t & 3;
    const int c = ct * 64 + cl;
    const float ga = gamma[c] * rstd;
    const float be = beta[c] - mean * ga;
    const float4* xp = (const float4*)(x + ((size_t)b * CCH + c) * NSP + nt * 64);
#pragma unroll
    for (int j = 0; j < 4; j++) {
        float4 v = xp[nc * 4 + j];
        int n = nc * 16 + j * 4;
        T[(n + 0) * 72 + cl] = f2bf(v.x * ga + be);
        T[(n + 1) * 72 + cl] = f2bf(v.y * ga + be);
        T[(n + 2) * 72 + cl] = f2bf(v.z * ga + be);
        T[(n + 3) * 72 + cl] = f2bf(v.w * ga + be);
    }
    __syncthreads();
    const int nl = t >> 2, cc = t & 3;
    unsigned short* dst = hn_t + ((size_t)b * NSP + nt * 64 + nl) * CCH + ct * 64 + cc * 16;
    const unsigned short* src = T + nl * 72 + cc * 16;
    *(uint4*)dst = *(const uint4*)src;
    *(uint4*)(dst + 8) = *(const uint4*)(src + 8);
}

// ---------------- QK GEMM: QKt[b][n][o] = hn_t[n][:] . Wqkv[o][:] + b[o] ----
__global__ __launch_bounds__(256) void gemm_qk_k(
    const unsigned short* __restrict__ hn_t, const unsigned short* __restrict__ wq,
    const float* __restrict__ bq, unsigned short* __restrict__ QKt) {
    __shared__ __align__(16) short Al[128 * BK], Bl[128 * BK];
    const int nt = blockIdx.x * 128, mt = blockIdx.y * 128, b = blockIdx.z;
    const unsigned short* Ag = hn_t + ((size_t)b * NSP + mt) * CCH;
    const unsigned short* Bg = wq + (size_t)nt * CCH;
    ACC_INIT(acc);
    gemm128_loop(Ag, Bg, CCH, CCH, CCH, Al, Bl, acc);
    unsigned short* Ob = QKt + (size_t)b * NSP * 1024;
    EPI_SETUP();
#pragma unroll
    for (int ni = 0; ni < 4; ni++) {
        int col = nt + wc + ni * 16 + fr;
        float bias = bq[col];
#pragma unroll
        for (int mi = 0; mi < 4; mi++) {
            int row = mt + wr + mi * 16 + rr0;
#pragma unroll
            for (int r = 0; r < 4; r++)
                Ob[(size_t)(row + r) * 1024 + col] = f2bf(acc[mi * 4 + ni][r] + bias);
        }
    }
}

// ---------------- V GEMM: V[b][o][n] = Wqkv[1024+o][:] . hn_t[n][:] + b ----
__global__ __launch_bounds__(256) void gemm_v_k(
    const unsigned short* __restrict__ hn_t, const unsigned short* __restrict__ wq,
    const float* __restrict__ bq, unsigned short* __restrict__ Vb) {
    __shared__ __align__(16) short Al[128 * BK], Bl[128 * BK];
    const int nt = blockIdx.x * 128, mt = blockIdx.y * 128, b = blockIdx.z;
    const unsigned short* Ag = wq + (size_t)(1024 + mt) * CCH;
    const unsigned short* Bg = hn_t + ((size_t)b * NSP + nt) * CCH;
    ACC_INIT(acc);
    gemm128_loop(Ag, Bg, CCH, CCH, CCH, Al, Bl, acc);
    unsigned short* Ob = Vb + (size_t)b * CCH * NSP;
    EPI_SETUP();
#pragma unroll
    for (int mi = 0; mi < 4; mi++) {
        int row = mt + wr + mi * 16 + rr0;
#pragma unroll
        for (int r = 0; r < 4; r++) {
            float bias = bq[1024 + row + r];
#pragma unroll
            for (int ni = 0; ni < 4; ni++) {
                int col = nt + wc + ni * 16 + fr;
                Ob[(size_t)(row + r) * NSP + col] = f2bf(acc[mi * 4 + ni][r] + bias);
            }
        }
    }
}

// ---------------- scores: S[b][n][m] = scale * Qt[n][:] . Kt[m][:] ----------
__global__ __launch_bounds__(256) void gemm_scores_k(
    const unsigned short* __restrict__ QKt, float* __restrict__ S) {
    __shared__ __align__(16) short Al[128 * BK], Bl[128 * BK];
    const int nt = blockIdx.x * 128, mt = blockIdx.y * 128, b = blockIdx.z;
    const unsigned short* base = QKt + (size_t)b * NSP * 1024;
    const unsigned short* Ag = base + (size_t)mt * 1024;        // Q rows
    const unsigned short* Bg = base + (size_t)nt * 1024 + 512;  // K rows
    ACC_INIT(acc);
    gemm128_loop(Ag, Bg, 1024, 1024, 512, Al, Bl, acc);
    float* Ob = S + (size_t)b * NSP * NSP;
    const float scale = 0.044194173824159216f;  // 512^-0.5
    EPI_SETUP();
#pragma unroll
    for (int mi = 0; mi < 4; mi++) {
        int row = mt + wr + mi * 16 + rr0;
#pragma unroll
        for (int ni = 0; ni < 4; ni++) {
            int col = nt + wc + ni * 16 + fr;
#pragma unroll
            for (int r = 0; r < 4; r++)
                Ob[(size_t)(row + r) * NSP + col] = acc[mi * 4 + ni][r] * scale;
        }
    }
}

// ---------------- softmax rows of S -> bf16 P ----------------
__global__ __launch_bounds__(256) void softmax_k(
    const float* __restrict__ S, unsigned short* __restrict__ P) {
    const int t = threadIdx.x;
    const float4* row = (const float4*)(S + (size_t)blockIdx.x * NSP);
    ushort4* prow = (ushort4*)(P + (size_t)blockIdx.x * NSP);
    float4 v = row[t];
    float m = fmaxf(fmaxf(v.x, v.y), fmaxf(v.z, v.w));
#pragma unroll
    for (int off = 32; off; off >>= 1) m = fmaxf(m, __shfl_down(m, off));
    __shared__ float red[4];
    __shared__ float bc;
    const int wave = t >> 6, lane = t & 63;
    if (lane == 0) red[wave] = m;
    __syncthreads();
    if (t == 0) bc = fmaxf(fmaxf(red[0], red[1]), fmaxf(red[2], red[3]));
    __syncthreads();
    const float M = bc;
    v.x = __expf(v.x - M);
    v.y = __expf(v.y - M);
    v.z = __expf(v.z - M);
    v.w = __expf(v.w - M);
    float s = v.x + v.y + v.z + v.w;
#pragma unroll
    for (int off = 32; off; off >>= 1) s += __shfl_down(s, off);
    __syncthreads();
    if (lane == 0) red[wave] = s;
    __syncthreads();
    if (t == 0) bc = red[0] + red[1] + red[2] + red[3];
    __syncthreads();
    const float inv = 1.f / bc;
    ushort4 o;
    o.x = f2bf(v.x * inv); o.y = f2bf(v.y * inv);
    o.z = f2bf(v.z * inv); o.w = f2bf(v.w * inv);
    prow[t] = o;
}

// ---------------- PV: At[b][n][c] = P[n][:] . V[c][:] ----------------
__global__ __launch_bounds__(256) void gemm_pv_k(
    const unsigned short* __restrict__ P, const unsigned short* __restrict__ Vb,
    unsigned short* __restrict__ At) {
    __shared__ __align__(16) short Al[128 * BK], Bl[128 * BK];
    const int nt = blockIdx.x * 128, mt = blockIdx.y * 128, b = blockIdx.z;
    const unsigned short* Ag = P + ((size_t)b * NSP + mt) * NSP;
    const unsigned short* Bg = Vb + ((size_t)b * CCH + nt) * NSP;
    ACC_INIT(acc);
    gemm128_loop(Ag, Bg, NSP, NSP, NSP, Al, Bl, acc);
    unsigned short* Ob = At + (size_t)b * NSP * CCH;
    EPI_SETUP();
#pragma unroll
    for (int mi = 0; mi < 4; mi++) {
        int row = mt + wr + mi * 16 + rr0;
#pragma unroll
        for (int ni = 0; ni < 4; ni++) {
            int col = nt + wc + ni * 16 + fr;
#pragma unroll
            for (int r = 0; r < 4; r++)
                Ob[(size_t)(row + r) * CCH + col] = f2bf(acc[mi * 4 + ni][r]);
        }
    }
}

// ---------------- proj: out = x + bp[o] + Wp[o][:] . At[n][:] ----------------
__global__ __launch_bounds__(256) void gemm_proj_k(
    const unsigned short* __restrict__ At, const unsigned short* __restrict__ wp,
    const float* __restrict__ bp, const float* __restrict__ x,
    float* __restrict__ out) {
    __shared__ __align__(16) short Al[128 * BK], Bl[128 * BK];
    const int nt = blockIdx.x * 128, mt = blockIdx.y * 128, b = blockIdx.z;
    const unsigned short* Ag = wp + (size_t)mt * CCH;
    const unsigned short* Bg = At + ((size_t)b * NSP + nt) * CCH;
    ACC_INIT(acc);
    gemm128_loop(Ag, Bg, CCH, CCH, CCH, Al, Bl, acc);
    const size_t bbase = (size_t)b * CCH * NSP;
    EPI_SETUP();
#pragma unroll
    for (int mi = 0; mi < 4; mi++) {
        int row = mt + wr + mi * 16 + rr0;
#pragma unroll
        for (int r = 0; r < 4; r++) {
            float bias = bp[row + r];
#pragma unroll
            for (int ni = 0; ni < 4; ni++) {
                int col = nt + wc + ni * 16 + fr;
                size_t idx = bbase + (size_t)(row + r) * NSP + col;
                out[idx] = x[idx] + bias + acc[mi * 4 + ni][r];
            }
        }
    }
}

extern "C" void kernel_launch(void* const* d_in, const int* in_sizes, int n_in,
                              void* d_out, int out_size, void* d_ws, size_t ws_size,
                              hipStream_t stream) {
    const float* x = (const float*)d_in[0];
    const float* gamma = (const float*)d_in[1];
    const float* beta = (const float*)d_in[2];
    const float* w_qkv = (const float*)d_in[3];
    const float* b_qkv = (const float*)d_in[4];
    const float* w_proj = (const float*)d_in[5];
    const float* b_proj = (const float*)d_in[6];
    float* out = (float*)d_out;

    char* ws = (char*)d_ws;
    const size_t MB = 1048576;
    unsigned short* wqkv_bf = (unsigned short*)ws;                 // 1.5 MiB
    unsigned short* wproj_bf = (unsigned short*)(ws + 1572864);    // 0.5 MiB
    float* stats = (float*)(ws + 2 * MB);                          // 1 KiB
    float* S = (float*)(ws + 4 * MB);                              // 64 MiB [4,68)
    unsigned short* hn_t = (unsigned short*)(ws + 4 * MB);         // 16 MiB (aliases S; dead before S written)
    unsigned short* QKt = (unsigned short*)(ws + 68 * MB);         // 32 MiB [68,100)
    unsigned short* P = QKt;                                       // 32 MiB (aliases QKt; dead before P written)
    unsigned short* Vb = (unsigned short*)(ws + 100 * MB);         // 16 MiB
    unsigned short* At = (unsigned short*)(ws + 116 * MB);         // 16 MiB -> ends 132 MiB

    cvt_bf16_k<<<768, 256, 0, stream>>>(w_qkv, wqkv_bf, 196608);
    cvt_bf16_k<<<256, 256, 0, stream>>>(w_proj, wproj_bf, 65536);
    gn_stats_k<<<128, 256, 0, stream>>>(x, stats);
    gn_tr_k<<<dim3(16, 8, BATCH), 256, 0, stream>>>(x, gamma, beta, stats, hn_t);
    gemm_qk_k<<<dim3(8, 8, BATCH), 256, 0, stream>>>(hn_t, wqkv_bf, b_qkv, QKt);
    gemm_v_k<<<dim3(8, 4, BATCH), 256, 0, stream>>>(hn_t, wqkv_bf, b_qkv, Vb);
    gemm_scores_k<<<dim3(8, 8, BATCH), 256, 0, stream>>>(QKt, S);
    softmax_k<<<BATCH * NSP, 256, 0, stream>>>(S, P);
    gemm_pv_k<<<dim3(4, 8, BATCH), 256, 0, stream>>>(P, Vb, At);
    gemm_proj_k<<<dim3(8, 4, BATCH), 256, 0, stream>>>(At, wproj_bf, b_proj, x, out);
}

// Round 3
// 239.985 us; speedup vs baseline: 1.7852x; 1.0772x over previous
//
#include <hip/hip_runtime.h>

// Attention block: B=16, C=512, N=1024(=32x32), GROUPS=8, EPS=1e-5
// All GEMMs NT-form bf16 MFMA (A[M][K] x B[N][K]^T), 128x128 tiles,
// global_load_lds width-16 staging (m97 pattern).
//
// R3: softmax kernel eliminated. Scores kernel writes expS=exp(scale*qk) bf16
// and accumulates per-row sums (Lsum, fp32 atomics); PV epilogue divides.
// Safe because |s| <~ 6 (normalized inputs, w ~ 1/sqrt(C)); exp never overflows
// and softmax is shift-invariant.
//
// Layouts: hn_t[B][N][C], QKt[B][N][1024]=[Q|K], V[B][C][N],
//          expS bf16 [B][N][N], At[B][N][C] (aliases dead hn_t).

#define BATCH 16
#define CCH 512
#define NSP 1024
#define EPSV 1e-5f
#define BK 32  // shorts per K-step

typedef short bf16x8 __attribute__((ext_vector_type(8)));
typedef float f32x4 __attribute__((ext_vector_type(4)));

__device__ __forceinline__ unsigned short f2bf(float f) {
    unsigned int u = __float_as_uint(f);
    u += 0x7FFF + ((u >> 16) & 1);  // RNE
    return (unsigned short)(u >> 16);
}

__device__ __forceinline__ void glds16(const void* g, void* l) {
    __builtin_amdgcn_global_load_lds(
        (const __attribute__((address_space(1))) unsigned int*)g,
        (__attribute__((address_space(3))) unsigned int*)l, 16, 0, 0);
}

// ---------------- shared 128x128 NT mainloop ----------------
__device__ __forceinline__ void gemm128_loop(
    const unsigned short* __restrict__ Ag, const unsigned short* __restrict__ Bg,
    int astr, int bstr, int ktot, short* Al, short* Bl, f32x4* acc) {
    const int t = threadIdx.x;
    const int w = t >> 6, lane = t & 63;
    const int wr = (w >> 1) * 64, wc = (w & 1) * 64;
    const int fr = lane & 15, fko = (lane >> 4) * 8;
    const int r0 = t >> 2;          // staging row (4 chunks/row)
    const int kc = (t & 3) * 8;     // staging k-offset (shorts)
    short* Alb0 = Al + w * 512;
    short* Alb1 = Al + 2048 + w * 512;
    short* Blb0 = Bl + w * 512;
    short* Blb1 = Bl + 2048 + w * 512;
    for (int k0 = 0; k0 < ktot; k0 += BK) {
        glds16(Ag + (size_t)r0 * astr + k0 + kc, Alb0);
        glds16(Ag + (size_t)(r0 + 64) * astr + k0 + kc, Alb1);
        glds16(Bg + (size_t)r0 * bstr + k0 + kc, Blb0);
        glds16(Bg + (size_t)(r0 + 64) * bstr + k0 + kc, Blb1);
        __syncthreads();
        bf16x8 af[4], bfr[4];
#pragma unroll
        for (int mi = 0; mi < 4; mi++)
            af[mi] = *(const bf16x8*)(Al + (wr + mi * 16 + fr) * BK + fko);
#pragma unroll
        for (int ni = 0; ni < 4; ni++)
            bfr[ni] = *(const bf16x8*)(Bl + (wc + ni * 16 + fr) * BK + fko);
#pragma unroll
        for (int mi = 0; mi < 4; mi++)
#pragma unroll
            for (int ni = 0; ni < 4; ni++)
                acc[mi * 4 + ni] = __builtin_amdgcn_mfma_f32_16x16x32_bf16(
                    af[mi], bfr[ni], acc[mi * 4 + ni], 0, 0, 0);
        __syncthreads();
    }
}

#define EPI_SETUP()                                          \
    const int t = threadIdx.x, lane = t & 63, w = t >> 6;    \
    const int wr = (w >> 1) * 64, wc = (w & 1) * 64;         \
    const int fr = lane & 15, rr0 = (lane >> 4) * 4;

#define ACC_INIT(acc)                                        \
    f32x4 acc[16];                                           \
    _Pragma("unroll") for (int i = 0; i < 16; i++)           \
        acc[i] = (f32x4){0.f, 0.f, 0.f, 0.f};

// ---------------- weights f32 -> bf16 (both arrays, one launch) ----------
__global__ __launch_bounds__(256) void cvt_bf16_k(
    const float* __restrict__ a, unsigned short* __restrict__ oa, int na4,
    const float* __restrict__ b, unsigned short* __restrict__ ob, int nb4) {
    int i = blockIdx.x * 256 + threadIdx.x;
    const float* src;
    unsigned short* dst;
    int j;
    if (i < na4) { src = a; dst = oa; j = i; }
    else { j = i - na4; if (j >= nb4) return; src = b; dst = ob; }
    float4 v = ((const float4*)src)[j];
    ushort4 o;
    o.x = f2bf(v.x); o.y = f2bf(v.y); o.z = f2bf(v.z); o.w = f2bf(v.w);
    ((ushort4*)dst)[j] = o;
}

// ---------------- GroupNorm stats: one block per (b,g) ----------------
__global__ __launch_bounds__(256) void gn_stats_k(
    const float* __restrict__ x, float* __restrict__ stats) {
    const int bg = blockIdx.x;
    const float4* xp = (const float4*)(x + (size_t)bg * 65536);
    const int t = threadIdx.x;
    float s = 0.f, q = 0.f;
#pragma unroll
    for (int i = 0; i < 64; i++) {
        float4 v = xp[t + i * 256];
        s += v.x + v.y + v.z + v.w;
        q += v.x * v.x + v.y * v.y + v.z * v.z + v.w * v.w;
    }
#pragma unroll
    for (int off = 32; off; off >>= 1) {
        s += __shfl_down(s, off);
        q += __shfl_down(q, off);
    }
    __shared__ float rs[4], rq[4];
    const int wave = t >> 6, lane = t & 63;
    if (lane == 0) { rs[wave] = s; rq[wave] = q; }
    __syncthreads();
    if (t == 0) {
        float S = rs[0] + rs[1] + rs[2] + rs[3];
        float Q = rq[0] + rq[1] + rq[2] + rq[3];
        const float inv = 1.f / 65536.f;
        float mean = S * inv;
        float var = Q * inv - mean * mean;
        stats[bg * 2] = mean;
        stats[bg * 2 + 1] = rsqrtf(var + EPSV);
    }
}

// ---------------- GN normalize + transpose -> hn_t[B][N][C] bf16 --------
__global__ __launch_bounds__(256) void gn_tr_k(
    const float* __restrict__ x, const float* __restrict__ gamma,
    const float* __restrict__ beta, const float* __restrict__ stats,
    unsigned short* __restrict__ hn_t) {
    const int nt = blockIdx.x, ct = blockIdx.y, b = blockIdx.z;
    __shared__ __align__(16) unsigned short T[64 * 72];  // [n][c] +pad
    const int t = threadIdx.x;
    const float mean = stats[(b * 8 + ct) * 2];
    const float rstd = stats[(b * 8 + ct) * 2 + 1];
    const int cl = t >> 2, nc = t & 3;
    const int c = ct * 64 + cl;
    const float ga = gamma[c] * rstd;
    const float be = beta[c] - mean * ga;
    const float4* xp = (const float4*)(x + ((size_t)b * CCH + c) * NSP + nt * 64);
#pragma unroll
    for (int j = 0; j < 4; j++) {
        float4 v = xp[nc * 4 + j];
        int n = nc * 16 + j * 4;
        T[(n + 0) * 72 + cl] = f2bf(v.x * ga + be);
        T[(n + 1) * 72 + cl] = f2bf(v.y * ga + be);
        T[(n + 2) * 72 + cl] = f2bf(v.z * ga + be);
        T[(n + 3) * 72 + cl] = f2bf(v.w * ga + be);
    }
    __syncthreads();
    const int nl = t >> 2, cc = t & 3;
    unsigned short* dst = hn_t + ((size_t)b * NSP + nt * 64 + nl) * CCH + ct * 64 + cc * 16;
    const unsigned short* src = T + nl * 72 + cc * 16;
    *(uint4*)dst = *(const uint4*)src;
    *(uint4*)(dst + 8) = *(const uint4*)(src + 8);
}

// ---------------- QKV (merged): y<8 -> Q|K rows, y>=8 -> V (transposed) ----
__global__ __launch_bounds__(256) void gemm_qkv_k(
    const unsigned short* __restrict__ hn_t, const unsigned short* __restrict__ wq,
    const float* __restrict__ bq, unsigned short* __restrict__ QKt,
    unsigned short* __restrict__ Vb) {
    __shared__ __align__(16) short Al[128 * BK], Bl[128 * BK];
    const int ntc = blockIdx.x * 128, y = blockIdx.y, b = blockIdx.z;
    ACC_INIT(acc);
    if (y < 8) {
        // QKt[b][n][o] = hn_t[n][:] . wq[o][:] + bq[o]
        const int mt = y * 128;
        gemm128_loop(hn_t + ((size_t)b * NSP + mt) * CCH,
                     wq + (size_t)ntc * CCH, CCH, CCH, CCH, Al, Bl, acc);
        unsigned short* Ob = QKt + (size_t)b * NSP * 1024;
        EPI_SETUP();
#pragma unroll
        for (int ni = 0; ni < 4; ni++) {
            int col = ntc + wc + ni * 16 + fr;
            float bias = bq[col];
#pragma unroll
            for (int mi = 0; mi < 4; mi++) {
                int row = mt + wr + mi * 16 + rr0;
#pragma unroll
                for (int r = 0; r < 4; r++)
                    Ob[(size_t)(row + r) * 1024 + col] = f2bf(acc[mi * 4 + ni][r] + bias);
            }
        }
    } else {
        // V[b][o][n] = wq[1024+o][:] . hn_t[n][:] + bq[1024+o]
        const int mt = (y - 8) * 128;
        gemm128_loop(wq + (size_t)(1024 + mt) * CCH,
                     hn_t + ((size_t)b * NSP + ntc) * CCH, CCH, CCH, CCH, Al, Bl, acc);
        unsigned short* Ob = Vb + (size_t)b * CCH * NSP;
        EPI_SETUP();
#pragma unroll
        for (int mi = 0; mi < 4; mi++) {
            int row = mt + wr + mi * 16 + rr0;
#pragma unroll
            for (int r = 0; r < 4; r++) {
                float bias = bq[1024 + row + r];
#pragma unroll
                for (int ni = 0; ni < 4; ni++) {
                    int col = ntc + wc + ni * 16 + fr;
                    Ob[(size_t)(row + r) * NSP + col] = f2bf(acc[mi * 4 + ni][r] + bias);
                }
            }
        }
    }
}

// ------- scores+exp: expS[b][n][m]=exp(scale*q.k) bf16; Lsum[b][n] += rowsum ----
__global__ __launch_bounds__(256) void gemm_scores_k(
    const unsigned short* __restrict__ QKt, unsigned short* __restrict__ expS,
    float* __restrict__ Lsum) {
    __shared__ __align__(16) short Al[128 * BK], Bl[128 * BK];
    const int nt = blockIdx.x * 128, mt = blockIdx.y * 128, b = blockIdx.z;
    const unsigned short* base = QKt + (size_t)b * NSP * 1024;
    ACC_INIT(acc);
    gemm128_loop(base + (size_t)mt * 1024, base + (size_t)nt * 1024 + 512,
                 1024, 1024, 512, Al, Bl, acc);
    unsigned short* Ob = expS + (size_t)b * NSP * NSP;
    float* Ls = Lsum + (size_t)b * NSP;
    const float scale = 0.044194173824159216f;  // 512^-0.5
    EPI_SETUP();
#pragma unroll
    for (int mi = 0; mi < 4; mi++) {
#pragma unroll
        for (int r = 0; r < 4; r++) {
            const int row = mt + wr + mi * 16 + rr0 + r;
            float rs = 0.f;
#pragma unroll
            for (int ni = 0; ni < 4; ni++) {
                int col = nt + wc + ni * 16 + fr;
                float e = __expf(acc[mi * 4 + ni][r] * scale);
                Ob[(size_t)row * NSP + col] = f2bf(e);
                rs += e;
            }
            rs += __shfl_xor(rs, 1);
            rs += __shfl_xor(rs, 2);
            rs += __shfl_xor(rs, 4);
            rs += __shfl_xor(rs, 8);
            if (fr == 0) atomicAdd(&Ls[row], rs);
        }
    }
}

// ---------------- PV: At[b][n][c] = (expS[n][:] . V[c][:]) / Lsum[n] --------
__global__ __launch_bounds__(256) void gemm_pv_k(
    const unsigned short* __restrict__ expS, const unsigned short* __restrict__ Vb,
    const float* __restrict__ Lsum, unsigned short* __restrict__ At) {
    __shared__ __align__(16) short Al[128 * BK], Bl[128 * BK];
    const int ntc = blockIdx.x * 128, mt = blockIdx.y * 128, b = blockIdx.z;
    ACC_INIT(acc);
    gemm128_loop(expS + ((size_t)b * NSP + mt) * NSP,
                 Vb + ((size_t)b * CCH + ntc) * NSP, NSP, NSP, NSP, Al, Bl, acc);
    unsigned short* Ob = At + (size_t)b * NSP * CCH;
    const float* Ls = Lsum + (size_t)b * NSP;
    EPI_SETUP();
#pragma unroll
    for (int mi = 0; mi < 4; mi++) {
        int row = mt + wr + mi * 16 + rr0;
#pragma unroll
        for (int r = 0; r < 4; r++) {
            float inv = __builtin_amdgcn_rcpf(Ls[row + r]);
#pragma unroll
            for (int ni = 0; ni < 4; ni++) {
                int col = ntc + wc + ni * 16 + fr;
                Ob[(size_t)(row + r) * CCH + col] = f2bf(acc[mi * 4 + ni][r] * inv);
            }
        }
    }
}

// ---------------- proj: out = x + bp[o] + Wp[o][:] . At[n][:] ----------------
__global__ __launch_bounds__(256) void gemm_proj_k(
    const unsigned short* __restrict__ At, const unsigned short* __restrict__ wp,
    const float* __restrict__ bp, const float* __restrict__ x,
    float* __restrict__ out) {
    __shared__ __align__(16) short Al[128 * BK], Bl[128 * BK];
    const int nt = blockIdx.x * 128, mt = blockIdx.y * 128, b = blockIdx.z;
    ACC_INIT(acc);
    gemm128_loop(wp + (size_t)mt * CCH, At + ((size_t)b * NSP + nt) * CCH,
                 CCH, CCH, CCH, Al, Bl, acc);
    const size_t bbase = (size_t)b * CCH * NSP;
    EPI_SETUP();
#pragma unroll
    for (int mi = 0; mi < 4; mi++) {
        int row = mt + wr + mi * 16 + rr0;
#pragma unroll
        for (int r = 0; r < 4; r++) {
            float bias = bp[row + r];
#pragma unroll
            for (int ni = 0; ni < 4; ni++) {
                int col = nt + wc + ni * 16 + fr;
                size_t idx = bbase + (size_t)(row + r) * NSP + col;
                out[idx] = x[idx] + bias + acc[mi * 4 + ni][r];
            }
        }
    }
}

extern "C" void kernel_launch(void* const* d_in, const int* in_sizes, int n_in,
                              void* d_out, int out_size, void* d_ws, size_t ws_size,
                              hipStream_t stream) {
    const float* x = (const float*)d_in[0];
    const float* gamma = (const float*)d_in[1];
    const float* beta = (const float*)d_in[2];
    const float* w_qkv = (const float*)d_in[3];
    const float* b_qkv = (const float*)d_in[4];
    const float* w_proj = (const float*)d_in[5];
    const float* b_proj = (const float*)d_in[6];
    float* out = (float*)d_out;

    char* ws = (char*)d_ws;
    const size_t MB = 1048576;
    unsigned short* wqkv_bf = (unsigned short*)ws;               // 1.5 MiB
    unsigned short* wproj_bf = (unsigned short*)(ws + 1572864);  // 0.5 MiB
    float* stats = (float*)(ws + 2 * MB);                        // 1 KiB
    float* Lsum = (float*)(ws + 2 * MB + 65536);                 // 64 KiB
    unsigned short* hn_t = (unsigned short*)(ws + 4 * MB);       // 16.8 MiB
    unsigned short* At = hn_t;                                   // aliases dead hn_t
    unsigned short* QKt = (unsigned short*)(ws + 24 * MB);       // 33.5 MiB
    unsigned short* Vb = (unsigned short*)(ws + 60 * MB);        // 16.8 MiB
    unsigned short* expS = (unsigned short*)(ws + 80 * MB);      // 33.5 MiB -> 113.5

    hipMemsetAsync(Lsum, 0, BATCH * NSP * sizeof(float), stream);
    cvt_bf16_k<<<1024, 256, 0, stream>>>(w_qkv, wqkv_bf, 196608, w_proj, wproj_bf, 65536);
    gn_stats_k<<<128, 256, 0, stream>>>(x, stats);
    gn_tr_k<<<dim3(16, 8, BATCH), 256, 0, stream>>>(x, gamma, beta, stats, hn_t);
    gemm_qkv_k<<<dim3(8, 12, BATCH), 256, 0, stream>>>(hn_t, wqkv_bf, b_qkv, QKt, Vb);
    gemm_scores_k<<<dim3(8, 8, BATCH), 256, 0, stream>>>(QKt, expS, Lsum);
    gemm_pv_k<<<dim3(4, 8, BATCH), 256, 0, stream>>>(expS, Vb, Lsum, At);
    gemm_proj_k<<<dim3(8, 4, BATCH), 256, 0, stream>>>(At, wproj_bf, b_proj, x, out);
}

// Round 4
// 225.674 us; speedup vs baseline: 1.8985x; 1.0634x over previous
//
#include <hip/hip_runtime.h>

// Attention block: B=16, C=512, N=1024(=32x32), GROUPS=8, EPS=1e-5
// All GEMMs NT-form bf16 MFMA (A[M][K] x B[N][K]^T), 128x128 tiles,
// global_load_lds width-16 staging (m97 pattern).
//
// R4: XCD-pinned block swizzle. Assuming round-robin dispatch (block i ->
// XCD i%8), decode (x,y,b) from a 1-D grid so every block of batch b lands
// on XCD b%8. Per-batch working sets (hn_t[b]=1MB, QKt[b]=2MB, expS[b]=2MB,
// Vb[b]=1MB) then fit the 4MB per-XCD L2 -> kills the cross-XCD re-fetch
// (R3: qkv FETCH 74MB vs ~20MB logical). Wrong mapping only costs locality.
//
// Layouts: hn_t[B][N][C], QKt[B][N][1024]=[Q|K], V[B][C][N],
//          expS bf16 [B][N][N], At[B][N][C] (aliases dead hn_t).

#define BATCH 16
#define CCH 512
#define NSP 1024
#define EPSV 1e-5f
#define BK 32  // shorts per K-step

typedef short bf16x8 __attribute__((ext_vector_type(8)));
typedef float f32x4 __attribute__((ext_vector_type(4)));

__device__ __forceinline__ unsigned short f2bf(float f) {
    unsigned int u = __float_as_uint(f);
    u += 0x7FFF + ((u >> 16) & 1);  // RNE
    return (unsigned short)(u >> 16);
}

__device__ __forceinline__ void glds16(const void* g, void* l) {
    __builtin_amdgcn_global_load_lds(
        (const __attribute__((address_space(1))) unsigned int*)g,
        (__attribute__((address_space(3))) unsigned int*)l, 16, 0, 0);
}

// Decode 1-D block id -> (x, y, b) with batch pinned to XCD (lin%8).
// PER = blocks per batch (= GX*GY); XLOG2 = log2(GX).
#define XCD_MAP(GX_LOG2, PER, xv, yv, bv)                 \
    const int lin_ = blockIdx.x;                          \
    const int xcd_ = lin_ & 7;                            \
    int slot_ = lin_ >> 3;                                \
    const int hi_ = (slot_ >= (PER)) ? 1 : 0;             \
    const int bv = xcd_ + 8 * hi_;                        \
    slot_ -= hi_ * (PER);                                 \
    const int xv = slot_ & ((1 << (GX_LOG2)) - 1);        \
    const int yv = slot_ >> (GX_LOG2);

// ---------------- shared 128x128 NT mainloop ----------------
__device__ __forceinline__ void gemm128_loop(
    const unsigned short* __restrict__ Ag, const unsigned short* __restrict__ Bg,
    int astr, int bstr, int ktot, short* Al, short* Bl, f32x4* acc) {
    const int t = threadIdx.x;
    const int w = t >> 6, lane = t & 63;
    const int wr = (w >> 1) * 64, wc = (w & 1) * 64;
    const int fr = lane & 15, fko = (lane >> 4) * 8;
    const int r0 = t >> 2;          // staging row (4 chunks/row)
    const int kc = (t & 3) * 8;     // staging k-offset (shorts)
    short* Alb0 = Al + w * 512;
    short* Alb1 = Al + 2048 + w * 512;
    short* Blb0 = Bl + w * 512;
    short* Blb1 = Bl + 2048 + w * 512;
    for (int k0 = 0; k0 < ktot; k0 += BK) {
        glds16(Ag + (size_t)r0 * astr + k0 + kc, Alb0);
        glds16(Ag + (size_t)(r0 + 64) * astr + k0 + kc, Alb1);
        glds16(Bg + (size_t)r0 * bstr + k0 + kc, Blb0);
        glds16(Bg + (size_t)(r0 + 64) * bstr + k0 + kc, Blb1);
        __syncthreads();
        bf16x8 af[4], bfr[4];
#pragma unroll
        for (int mi = 0; mi < 4; mi++)
            af[mi] = *(const bf16x8*)(Al + (wr + mi * 16 + fr) * BK + fko);
#pragma unroll
        for (int ni = 0; ni < 4; ni++)
            bfr[ni] = *(const bf16x8*)(Bl + (wc + ni * 16 + fr) * BK + fko);
#pragma unroll
        for (int mi = 0; mi < 4; mi++)
#pragma unroll
            for (int ni = 0; ni < 4; ni++)
                acc[mi * 4 + ni] = __builtin_amdgcn_mfma_f32_16x16x32_bf16(
                    af[mi], bfr[ni], acc[mi * 4 + ni], 0, 0, 0);
        __syncthreads();
    }
}

#define EPI_SETUP()                                          \
    const int t = threadIdx.x, lane = t & 63, w = t >> 6;    \
    const int wr = (w >> 1) * 64, wc = (w & 1) * 64;         \
    const int fr = lane & 15, rr0 = (lane >> 4) * 4;

#define ACC_INIT(acc)                                        \
    f32x4 acc[16];                                           \
    _Pragma("unroll") for (int i = 0; i < 16; i++)           \
        acc[i] = (f32x4){0.f, 0.f, 0.f, 0.f};

// ------- setup: GN stats (blocks 0..127) + weight cvt (blocks 128..) -------
__global__ __launch_bounds__(256) void setup_k(
    const float* __restrict__ x, float* __restrict__ stats,
    const float* __restrict__ wa, unsigned short* __restrict__ oa, int na4,
    const float* __restrict__ wb, unsigned short* __restrict__ ob, int nb4) {
    const int t = threadIdx.x;
    if (blockIdx.x < 128) {
        const int bg = blockIdx.x;
        const float4* xp = (const float4*)(x + (size_t)bg * 65536);
        float s = 0.f, q = 0.f;
#pragma unroll
        for (int i = 0; i < 64; i++) {
            float4 v = xp[t + i * 256];
            s += v.x + v.y + v.z + v.w;
            q += v.x * v.x + v.y * v.y + v.z * v.z + v.w * v.w;
        }
#pragma unroll
        for (int off = 32; off; off >>= 1) {
            s += __shfl_down(s, off);
            q += __shfl_down(q, off);
        }
        __shared__ float rs[4], rq[4];
        const int wave = t >> 6, lane = t & 63;
        if (lane == 0) { rs[wave] = s; rq[wave] = q; }
        __syncthreads();
        if (t == 0) {
            float S = rs[0] + rs[1] + rs[2] + rs[3];
            float Q = rq[0] + rq[1] + rq[2] + rq[3];
            const float inv = 1.f / 65536.f;
            float mean = S * inv;
            float var = Q * inv - mean * mean;
            stats[bg * 2] = mean;
            stats[bg * 2 + 1] = rsqrtf(var + EPSV);
        }
    } else {
        int i = (blockIdx.x - 128) * 256 + t;
        const float* src;
        unsigned short* dst;
        int j;
        if (i < na4) { src = wa; dst = oa; j = i; }
        else { j = i - na4; if (j >= nb4) return; src = wb; dst = ob; }
        float4 v = ((const float4*)src)[j];
        ushort4 o;
        o.x = f2bf(v.x); o.y = f2bf(v.y); o.z = f2bf(v.z); o.w = f2bf(v.w);
        ((ushort4*)dst)[j] = o;
    }
}

// ---------------- GN normalize + transpose -> hn_t[B][N][C] bf16 --------
__global__ __launch_bounds__(256) void gn_tr_k(
    const float* __restrict__ x, const float* __restrict__ gamma,
    const float* __restrict__ beta, const float* __restrict__ stats,
    unsigned short* __restrict__ hn_t) {
    const int nt = blockIdx.x, ct = blockIdx.y, b = blockIdx.z;
    __shared__ __align__(16) unsigned short T[64 * 72];  // [n][c] +pad
    const int t = threadIdx.x;
    const float mean = stats[(b * 8 + ct) * 2];
    const float rstd = stats[(b * 8 + ct) * 2 + 1];
    const int cl = t >> 2, nc = t & 3;
    const int c = ct * 64 + cl;
    const float ga = gamma[c] * rstd;
    const float be = beta[c] - mean * ga;
    const float4* xp = (const float4*)(x + ((size_t)b * CCH + c) * NSP + nt * 64);
#pragma unroll
    for (int j = 0; j < 4; j++) {
        float4 v = xp[nc * 4 + j];
        int n = nc * 16 + j * 4;
        T[(n + 0) * 72 + cl] = f2bf(v.x * ga + be);
        T[(n + 1) * 72 + cl] = f2bf(v.y * ga + be);
        T[(n + 2) * 72 + cl] = f2bf(v.z * ga + be);
        T[(n + 3) * 72 + cl] = f2bf(v.w * ga + be);
    }
    __syncthreads();
    const int nl = t >> 2, cc = t & 3;
    unsigned short* dst = hn_t + ((size_t)b * NSP + nt * 64 + nl) * CCH + ct * 64 + cc * 16;
    const unsigned short* src = T + nl * 72 + cc * 16;
    *(uint4*)dst = *(const uint4*)src;
    *(uint4*)(dst + 8) = *(const uint4*)(src + 8);
}

// ---------------- QKV (merged): y<8 -> Q|K rows, y>=8 -> V (transposed) ----
// grid: 1536 blocks, GX=8 (ntc), GY=12 (y), PER=96
__global__ __launch_bounds__(256) void gemm_qkv_k(
    const unsigned short* __restrict__ hn_t, const unsigned short* __restrict__ wq,
    const float* __restrict__ bq, unsigned short* __restrict__ QKt,
    unsigned short* __restrict__ Vb) {
    __shared__ __align__(16) short Al[128 * BK], Bl[128 * BK];
    XCD_MAP(3, 96, xb, y, b);
    const int ntc = xb * 128;
    ACC_INIT(acc);
    if (y < 8) {
        // QKt[b][n][o] = hn_t[n][:] . wq[o][:] + bq[o]
        const int mt = y * 128;
        gemm128_loop(hn_t + ((size_t)b * NSP + mt) * CCH,
                     wq + (size_t)ntc * CCH, CCH, CCH, CCH, Al, Bl, acc);
        unsigned short* Ob = QKt + (size_t)b * NSP * 1024;
        EPI_SETUP();
#pragma unroll
        for (int ni = 0; ni < 4; ni++) {
            int col = ntc + wc + ni * 16 + fr;
            float bias = bq[col];
#pragma unroll
            for (int mi = 0; mi < 4; mi++) {
                int row = mt + wr + mi * 16 + rr0;
#pragma unroll
                for (int r = 0; r < 4; r++)
                    Ob[(size_t)(row + r) * 1024 + col] = f2bf(acc[mi * 4 + ni][r] + bias);
            }
        }
    } else {
        // V[b][o][n] = wq[1024+o][:] . hn_t[n][:] + bq[1024+o]
        const int mt = (y - 8) * 128;
        gemm128_loop(wq + (size_t)(1024 + mt) * CCH,
                     hn_t + ((size_t)b * NSP + ntc) * CCH, CCH, CCH, CCH, Al, Bl, acc);
        unsigned short* Ob = Vb + (size_t)b * CCH * NSP;
        EPI_SETUP();
#pragma unroll
        for (int mi = 0; mi < 4; mi++) {
            int row = mt + wr + mi * 16 + rr0;
#pragma unroll
            for (int r = 0; r < 4; r++) {
                float bias = bq[1024 + row + r];
#pragma unroll
                for (int ni = 0; ni < 4; ni++) {
                    int col = ntc + wc + ni * 16 + fr;
                    Ob[(size_t)(row + r) * NSP + col] = f2bf(acc[mi * 4 + ni][r] + bias);
                }
            }
        }
    }
}

// ------- scores+exp: expS[b][n][m]=exp(scale*q.k) bf16; Lsum[b][n] += rowsum ----
// grid: 1024 blocks, GX=8 (nt), GY=8 (mt), PER=64
__global__ __launch_bounds__(256) void gemm_scores_k(
    const unsigned short* __restrict__ QKt, unsigned short* __restrict__ expS,
    float* __restrict__ Lsum) {
    __shared__ __align__(16) short Al[128 * BK], Bl[128 * BK];
    XCD_MAP(3, 64, xb, yb, b);
    const int nt = xb * 128, mt = yb * 128;
    const unsigned short* base = QKt + (size_t)b * NSP * 1024;
    ACC_INIT(acc);
    gemm128_loop(base + (size_t)mt * 1024, base + (size_t)nt * 1024 + 512,
                 1024, 1024, 512, Al, Bl, acc);
    unsigned short* Ob = expS + (size_t)b * NSP * NSP;
    float* Ls = Lsum + (size_t)b * NSP;
    const float scale = 0.044194173824159216f;  // 512^-0.5
    EPI_SETUP();
#pragma unroll
    for (int mi = 0; mi < 4; mi++) {
#pragma unroll
        for (int r = 0; r < 4; r++) {
            const int row = mt + wr + mi * 16 + rr0 + r;
            float rs = 0.f;
#pragma unroll
            for (int ni = 0; ni < 4; ni++) {
                int col = nt + wc + ni * 16 + fr;
                float e = __expf(acc[mi * 4 + ni][r] * scale);
                Ob[(size_t)row * NSP + col] = f2bf(e);
                rs += e;
            }
            rs += __shfl_xor(rs, 1);
            rs += __shfl_xor(rs, 2);
            rs += __shfl_xor(rs, 4);
            rs += __shfl_xor(rs, 8);
            if (fr == 0) atomicAdd(&Ls[row], rs);
        }
    }
}

// ---------------- PV: At[b][n][c] = (expS[n][:] . V[c][:]) / Lsum[n] --------
// grid: 512 blocks, GX=4 (ntc), GY=8 (mt), PER=32
__global__ __launch_bounds__(256) void gemm_pv_k(
    const unsigned short* __restrict__ expS, const unsigned short* __restrict__ Vb,
    const float* __restrict__ Lsum, unsigned short* __restrict__ At) {
    __shared__ __align__(16) short Al[128 * BK], Bl[128 * BK];
    XCD_MAP(2, 32, xb, yb, b);
    const int ntc = xb * 128, mt = yb * 128;
    ACC_INIT(acc);
    gemm128_loop(expS + ((size_t)b * NSP + mt) * NSP,
                 Vb + ((size_t)b * CCH + ntc) * NSP, NSP, NSP, NSP, Al, Bl, acc);
    unsigned short* Ob = At + (size_t)b * NSP * CCH;
    const float* Ls = Lsum + (size_t)b * NSP;
    EPI_SETUP();
#pragma unroll
    for (int mi = 0; mi < 4; mi++) {
        int row = mt + wr + mi * 16 + rr0;
#pragma unroll
        for (int r = 0; r < 4; r++) {
            float inv = __builtin_amdgcn_rcpf(Ls[row + r]);
#pragma unroll
            for (int ni = 0; ni < 4; ni++) {
                int col = ntc + wc + ni * 16 + fr;
                Ob[(size_t)(row + r) * CCH + col] = f2bf(acc[mi * 4 + ni][r] * inv);
            }
        }
    }
}

// ---------------- proj: out = x + bp[o] + Wp[o][:] . At[n][:] ----------------
// grid: 512 blocks, GX=8 (nt), GY=4 (mt), PER=32
__global__ __launch_bounds__(256) void gemm_proj_k(
    const unsigned short* __restrict__ At, const unsigned short* __restrict__ wp,
    const float* __restrict__ bp, const float* __restrict__ x,
    float* __restrict__ out) {
    __shared__ __align__(16) short Al[128 * BK], Bl[128 * BK];
    XCD_MAP(3, 32, xb, yb, b);
    const int nt = xb * 128, mt = yb * 128;
    ACC_INIT(acc);
    gemm128_loop(wp + (size_t)mt * CCH, At + ((size_t)b * NSP + nt) * CCH,
                 CCH, CCH, CCH, Al, Bl, acc);
    const size_t bbase = (size_t)b * CCH * NSP;
    EPI_SETUP();
#pragma unroll
    for (int mi = 0; mi < 4; mi++) {
        int row = mt + wr + mi * 16 + rr0;
#pragma unroll
        for (int r = 0; r < 4; r++) {
            float bias = bp[row + r];
#pragma unroll
            for (int ni = 0; ni < 4; ni++) {
                int col = nt + wc + ni * 16 + fr;
                size_t idx = bbase + (size_t)(row + r) * NSP + col;
                out[idx] = x[idx] + bias + acc[mi * 4 + ni][r];
            }
        }
    }
}

extern "C" void kernel_launch(void* const* d_in, const int* in_sizes, int n_in,
                              void* d_out, int out_size, void* d_ws, size_t ws_size,
                              hipStream_t stream) {
    const float* x = (const float*)d_in[0];
    const float* gamma = (const float*)d_in[1];
    const float* beta = (const float*)d_in[2];
    const float* w_qkv = (const float*)d_in[3];
    const float* b_qkv = (const float*)d_in[4];
    const float* w_proj = (const float*)d_in[5];
    const float* b_proj = (const float*)d_in[6];
    float* out = (float*)d_out;

    char* ws = (char*)d_ws;
    const size_t MB = 1048576;
    unsigned short* wqkv_bf = (unsigned short*)ws;               // 1.5 MiB
    unsigned short* wproj_bf = (unsigned short*)(ws + 1572864);  // 0.5 MiB
    float* stats = (float*)(ws + 2 * MB);                        // 1 KiB
    float* Lsum = (float*)(ws + 2 * MB + 65536);                 // 64 KiB
    unsigned short* hn_t = (unsigned short*)(ws + 4 * MB);       // 16.8 MiB
    unsigned short* At = hn_t;                                   // aliases dead hn_t
    unsigned short* QKt = (unsigned short*)(ws + 24 * MB);       // 33.5 MiB
    unsigned short* Vb = (unsigned short*)(ws + 60 * MB);        // 16.8 MiB
    unsigned short* expS = (unsigned short*)(ws + 80 * MB);      // 33.5 MiB -> 113.5

    hipMemsetAsync(Lsum, 0, BATCH * NSP * sizeof(float), stream);
    setup_k<<<1152, 256, 0, stream>>>(x, stats, w_qkv, wqkv_bf, 196608,
                                      w_proj, wproj_bf, 65536);
    gn_tr_k<<<dim3(16, 8, BATCH), 256, 0, stream>>>(x, gamma, beta, stats, hn_t);
    gemm_qkv_k<<<1536, 256, 0, stream>>>(hn_t, wqkv_bf, b_qkv, QKt, Vb);
    gemm_scores_k<<<1024, 256, 0, stream>>>(QKt, expS, Lsum);
    gemm_pv_k<<<512, 256, 0, stream>>>(expS, Vb, Lsum, At);
    gemm_proj_k<<<512, 256, 0, stream>>>(At, wproj_bf, b_proj, x, out);
}